// Round 1
// baseline (152.567 us; speedup 1.0000x reference)
//
#include <hip/hip_runtime.h>

#define GAMMA 0.99f
#define LAM   0.95f

constexpr int BLOCK = 256;
constexpr int CHUNK = 8;           // timesteps per thread; requires T == BLOCK*CHUNK
constexpr int NWAVES = BLOCK / 64;

typedef float f32x4 __attribute__((ext_vector_type(4)));

// One block per row (B blocks). Thread i owns columns [i*CHUNK, i*CHUNK+CHUNK).
// Backward linear recurrence parallelized via affine composition:
//   g[t] = delta[t] + c[t]*g[t+1]  ==>  chunk maps incoming g to a + m*g.
//
// MLP design: ALL memory (2x float4 rewards, 2x float4 values, 2x int4 done,
// predicated boundary scalars) is issued before any consumption. done[t+1]
// comes from the aligned int4 pair shifted in-register; the single
// cross-thread element comes from __shfl_down (intra-wave) or a predicated
// lane-63 scalar load (cross-wave), both issued up front.
__global__ __launch_bounds__(BLOCK, 8) void gae_scan_kernel(
    const float* __restrict__ rewards,
    const float* __restrict__ values,
    const float* __restrict__ next_value,
    const int*   __restrict__ done,
    float* __restrict__ adv_out,
    float* __restrict__ ret_out,
    int T)
{
    const int row  = blockIdx.x;
    const int tid  = threadIdx.x;
    const int lane = tid & 63;
    const int wave = tid >> 6;

    const long rowbase = (long)row * T;
    const int  col0    = tid * CHUNK;

    // ---- issue ALL loads up front (independent, vectorized) ----
    const float4* r4 = reinterpret_cast<const float4*>(rewards + rowbase + col0);
    const float4* v4 = reinterpret_cast<const float4*>(values  + rowbase + col0);
    const int4*   d4 = reinterpret_cast<const int4*>(done      + rowbase + col0);
    float4 ra = r4[0], rb = r4[1];
    float4 va = v4[0], vb = v4[1];
    int4   da = d4[0], db = d4[1];

    // boundary (col0+CHUNK) values for wave-edge lanes — predicated, issued early.
    // bcol clamp keeps the address in-bounds; the clamped value is exactly what
    // the T-1 boundary needs for done (nnt[T-1] = 1 - d[T-1]).
    float bv = 0.0f; int bd = 0;
    if (lane == 63) {
        const int bcol = (col0 + CHUNK < T) ? (col0 + CHUNK) : (T - 1);
        bv = values[rowbase + bcol];
        bd = done[rowbase + bcol];
    }
    float vboot = 0.0f;
    if (tid == BLOCK - 1) vboot = next_value[row];

    // neighbor thread's first elements via intra-wave shuffle
    float v_nb = __shfl_down(va.x, 1);
    int   d_nb = __shfl_down(da.x, 1);

    float vnext  = (lane == 63) ? bv : v_nb;        // values[col0+CHUNK]
    float dnextf = (float)((lane == 63) ? bd : d_nb); // done[col0+CHUNK] (clamped T-1 at row end)
    if (tid == BLOCK - 1) vnext = vboot;            // bootstrap next_value at t=T-1

    float v[CHUNK];
    v[0]=va.x; v[1]=va.y; v[2]=va.z; v[3]=va.w;
    v[4]=vb.x; v[5]=vb.y; v[6]=vb.z; v[7]=vb.w;
    float r[CHUNK];
    r[0]=ra.x; r[1]=ra.y; r[2]=ra.z; r[3]=ra.w;
    r[4]=rb.x; r[5]=rb.y; r[6]=rb.z; r[7]=rb.w;
    // done[tcol+1] for each owned tcol (in-register shift of the int4 pair)
    float dn[CHUNK];
    dn[0]=(float)da.y; dn[1]=(float)da.z; dn[2]=(float)da.w; dn[3]=(float)db.x;
    dn[4]=(float)db.y; dn[5]=(float)db.z; dn[6]=(float)db.w; dn[7]=dnextf;
    float nv[CHUNK];
    nv[0]=v[1]; nv[1]=v[2]; nv[2]=v[3]; nv[3]=v[4];
    nv[4]=v[5]; nv[5]=v[6]; nv[6]=v[7]; nv[7]=vnext;

    // ---- delta[t] and c[t] ----
    float delta[CHUNK], c[CHUNK];
#pragma unroll
    for (int j = 0; j < CHUNK; ++j) {
        const float nnt = 1.0f - dn[j];
        delta[j] = r[j] + GAMMA * nv[j] * nnt - v[j];
        c[j]     = (GAMMA * LAM) * nnt;
    }

    // ---- per-thread affine composition over the chunk (backward) ----
    float a = 0.0f, m = 1.0f;
#pragma unroll
    for (int j = CHUNK - 1; j >= 0; --j) {
        a = delta[j] + c[j] * a;
        m = c[j] * m;
    }

    // ---- wave-level inclusive SUFFIX scan of affine fns (self ∘ higher-lane) ----
    float sa = a, sm = m;
#pragma unroll
    for (int d = 1; d < 64; d <<= 1) {
        float oa = __shfl_down(sa, d);
        float om = __shfl_down(sm, d);
        if (lane + d < 64) { sa = sa + sm * oa; sm = sm * om; }
    }
    // exclusive-within-wave (function of all higher lanes in this wave)
    float ea = __shfl_down(sa, 1);
    float em = __shfl_down(sm, 1);
    if (lane == 63) { ea = 0.0f; em = 1.0f; }

    // ---- cross-wave composition via LDS (wave totals live in lane 0's sa/sm) ----
    __shared__ float lds_a[NWAVES];
    __shared__ float lds_m[NWAVES];
    if (lane == 0) { lds_a[wave] = sa; lds_m[wave] = sm; }
    __syncthreads();

    float g = 0.0f;                       // gae entering from waves above this one
    for (int j = NWAVES - 1; j > wave; --j)
        g = lds_a[j] + lds_m[j] * g;
    float gin = ea + em * g;              // gae entering this thread's chunk

    // ---- replay: exact sequential recurrence over the chunk (in-place) ----
#pragma unroll
    for (int j = CHUNK - 1; j >= 0; --j) {
        gin = delta[j] + c[j] * gin;
        delta[j] = gin;                   // delta[] now holds advantages
    }

    // ---- non-temporal vectorized stores (outputs are never re-read; keep
    //      the 96MB of inputs resident in L3 across iterations) ----
    f32x4* a4 = reinterpret_cast<f32x4*>(adv_out + rowbase + col0);
    f32x4* t4 = reinterpret_cast<f32x4*>(ret_out + rowbase + col0);
    f32x4 o0 = { delta[0], delta[1], delta[2], delta[3] };
    f32x4 o1 = { delta[4], delta[5], delta[6], delta[7] };
    f32x4 s0 = { delta[0]+v[0], delta[1]+v[1], delta[2]+v[2], delta[3]+v[3] };
    f32x4 s1 = { delta[4]+v[4], delta[5]+v[5], delta[6]+v[6], delta[7]+v[7] };
    __builtin_nontemporal_store(o0, a4);
    __builtin_nontemporal_store(o1, a4 + 1);
    __builtin_nontemporal_store(s0, t4);
    __builtin_nontemporal_store(s1, t4 + 1);
}

// Fallback for shapes where T != BLOCK*CHUNK: one thread per row, sequential.
__global__ void gae_naive_kernel(
    const float* __restrict__ rewards,
    const float* __restrict__ values,
    const float* __restrict__ next_value,
    const int*   __restrict__ done,
    float* __restrict__ adv_out,
    float* __restrict__ ret_out,
    int B, int T)
{
    int row = blockIdx.x * blockDim.x + threadIdx.x;
    if (row >= B) return;
    long base = (long)row * T;
    float g = 0.0f;
    for (int t = T - 1; t >= 0; --t) {
        int dcol = (t + 1 < T) ? (t + 1) : (T - 1);
        float nnt = 1.0f - (float)done[base + dcol];
        float nv  = (t + 1 < T) ? values[base + t + 1] : next_value[row];
        float dl  = rewards[base + t] + GAMMA * nv * nnt - values[base + t];
        g = dl + (GAMMA * LAM) * nnt * g;
        adv_out[base + t] = g;
        ret_out[base + t] = g + values[base + t];
    }
}

extern "C" void kernel_launch(void* const* d_in, const int* in_sizes, int n_in,
                              void* d_out, int out_size, void* d_ws, size_t ws_size,
                              hipStream_t stream) {
    const float* rewards    = (const float*)d_in[0];
    const float* values     = (const float*)d_in[1];
    const float* next_value = (const float*)d_in[2];
    const int*   done       = (const int*)d_in[3];

    const int B = in_sizes[2];               // next_value is [B]
    const int T = in_sizes[0] / B;           // rewards is [B, T]

    float* adv = (float*)d_out;
    float* ret = adv + (long)B * T;

    if (T == BLOCK * CHUNK) {
        gae_scan_kernel<<<B, BLOCK, 0, stream>>>(
            rewards, values, next_value, done, adv, ret, T);
    } else {
        gae_naive_kernel<<<(B + 255) / 256, 256, 0, stream>>>(
            rewards, values, next_value, done, adv, ret, B, T);
    }
}

// Round 2
// 150.629 us; speedup vs baseline: 1.0129x; 1.0129x over previous
//
#include <hip/hip_runtime.h>

#define GAMMA 0.99f
#define LAM   0.95f

constexpr int BLOCK  = 256;
constexpr int CHUNK  = 8;            // timesteps per thread; requires T == BLOCK*CHUNK
constexpr int NWAVES = BLOCK / 64;
constexpr int GRID_TARGET = 1024;    // 4 blocks/CU on 256 CUs -> whole grid resident

typedef float f32x4 __attribute__((ext_vector_type(4)));

// Per-row register state (double-buffered across the row loop).
struct RowRegs {
    float4 ra, rb, va, vb;
    int4   da, db;
    float  bv;    // values[col0+CHUNK]            (lane 63 only)
    int    bd;    // done[min(col0+CHUNK, T-1)]    (lane 63 only)
    float  vboot; // next_value[row]               (tid == BLOCK-1 only)
};

__device__ __forceinline__ void load_row(
    const float* __restrict__ rewards, const float* __restrict__ values,
    const float* __restrict__ next_value, const int* __restrict__ done,
    int row, int T, int col0, int lane, int tid, RowRegs& R)
{
    const long rowbase = (long)row * T;
    const float4* r4 = reinterpret_cast<const float4*>(rewards + rowbase + col0);
    const float4* v4 = reinterpret_cast<const float4*>(values  + rowbase + col0);
    const int4*   d4 = reinterpret_cast<const int4*>(done      + rowbase + col0);
    R.ra = r4[0]; R.rb = r4[1];
    R.va = v4[0]; R.vb = v4[1];
    R.da = d4[0]; R.db = d4[1];
    if (lane == 63) {
        const int bcol = (col0 + CHUNK < T) ? (col0 + CHUNK) : (T - 1);
        R.bv = values[rowbase + bcol];
        R.bd = done[rowbase + bcol];
    }
    if (tid == BLOCK - 1) R.vboot = next_value[row];
}

// One block handles rows {blockIdx.x + k*gridDim.x}. Backward linear recurrence
// g[t] = delta[t] + c[t]*g[t+1] parallelized via affine composition; loads for
// the NEXT row are issued before the scan/store of the current row so every
// wave keeps ~6 vector loads in flight for its whole (long) lifetime.
__global__ __launch_bounds__(BLOCK, 4) void gae_scan_kernel(
    const float* __restrict__ rewards,
    const float* __restrict__ values,
    const float* __restrict__ next_value,
    const int*   __restrict__ done,
    float* __restrict__ adv_out,
    float* __restrict__ ret_out,
    int B, int T)
{
    const int tid  = threadIdx.x;
    const int lane = tid & 63;
    const int wave = tid >> 6;
    const int col0 = tid * CHUNK;

    __shared__ float lds_a[2][NWAVES];
    __shared__ float lds_m[2][NWAVES];

    RowRegs cur, nxt;
    load_row(rewards, values, next_value, done, blockIdx.x, T, col0, lane, tid, cur);

    int parity = 0;
    for (int row = blockIdx.x; row < B; row += gridDim.x) {
        // ---- prefetch next row while we compute this one ----
        const int nrow = row + gridDim.x;
        if (nrow < B)
            load_row(rewards, values, next_value, done, nrow, T, col0, lane, tid, nxt);

        const long rowbase = (long)row * T;

        // ---- unpack current row ----
        float v[CHUNK], r[CHUNK];
        v[0]=cur.va.x; v[1]=cur.va.y; v[2]=cur.va.z; v[3]=cur.va.w;
        v[4]=cur.vb.x; v[5]=cur.vb.y; v[6]=cur.vb.z; v[7]=cur.vb.w;
        r[0]=cur.ra.x; r[1]=cur.ra.y; r[2]=cur.ra.z; r[3]=cur.ra.w;
        r[4]=cur.rb.x; r[5]=cur.rb.y; r[6]=cur.rb.z; r[7]=cur.rb.w;

        // neighbor thread's first elements via intra-wave shuffle
        const float v_nb = __shfl_down(cur.va.x, 1);
        const int   d_nb = __shfl_down(cur.da.x, 1);
        float vnext  = (lane == 63) ? cur.bv : v_nb;          // values[col0+CHUNK]
        float dnextf = (float)((lane == 63) ? cur.bd : d_nb); // done[col0+CHUNK]
        if (tid == BLOCK - 1) vnext = cur.vboot;              // bootstrap at t=T-1

        float dn[CHUNK];  // done[tcol+1] per owned tcol (in-register shift)
        dn[0]=(float)cur.da.y; dn[1]=(float)cur.da.z; dn[2]=(float)cur.da.w; dn[3]=(float)cur.db.x;
        dn[4]=(float)cur.db.y; dn[5]=(float)cur.db.z; dn[6]=(float)cur.db.w; dn[7]=dnextf;
        float nv[CHUNK];
        nv[0]=v[1]; nv[1]=v[2]; nv[2]=v[3]; nv[3]=v[4];
        nv[4]=v[5]; nv[5]=v[6]; nv[6]=v[7]; nv[7]=vnext;

        // ---- delta[t] and c[t] ----
        float delta[CHUNK], c[CHUNK];
#pragma unroll
        for (int j = 0; j < CHUNK; ++j) {
            const float nnt = 1.0f - dn[j];
            delta[j] = r[j] + GAMMA * nv[j] * nnt - v[j];
            c[j]     = (GAMMA * LAM) * nnt;
        }

        // ---- per-thread affine composition over the chunk (backward) ----
        float a = 0.0f, m = 1.0f;
#pragma unroll
        for (int j = CHUNK - 1; j >= 0; --j) {
            a = delta[j] + c[j] * a;
            m = c[j] * m;
        }

        // ---- wave-level inclusive SUFFIX scan of affine fns ----
        float sa = a, sm = m;
#pragma unroll
        for (int d = 1; d < 64; d <<= 1) {
            float oa = __shfl_down(sa, d);
            float om = __shfl_down(sm, d);
            if (lane + d < 64) { sa = sa + sm * oa; sm = sm * om; }
        }
        float ea = __shfl_down(sa, 1);   // exclusive-within-wave
        float em = __shfl_down(sm, 1);
        if (lane == 63) { ea = 0.0f; em = 1.0f; }

        // ---- cross-wave composition via parity-buffered LDS ----
        if (lane == 0) { lds_a[parity][wave] = sa; lds_m[parity][wave] = sm; }
        __syncthreads();
        float g = 0.0f;
        for (int j = NWAVES - 1; j > wave; --j)
            g = lds_a[parity][j] + lds_m[parity][j] * g;
        float gin = ea + em * g;         // gae entering this thread's chunk

        // ---- replay: exact sequential recurrence over the chunk ----
#pragma unroll
        for (int j = CHUNK - 1; j >= 0; --j) {
            gin = delta[j] + c[j] * gin;
            delta[j] = gin;              // delta[] now holds advantages
        }

        // ---- vectorized stores (regular cached stores; NT was a measured
        //      regression: +23% WRITE_SIZE from unmerged partial lines) ----
        float4* a4 = reinterpret_cast<float4*>(adv_out + rowbase + col0);
        float4* t4 = reinterpret_cast<float4*>(ret_out + rowbase + col0);
        a4[0] = make_float4(delta[0], delta[1], delta[2], delta[3]);
        a4[1] = make_float4(delta[4], delta[5], delta[6], delta[7]);
        t4[0] = make_float4(delta[0]+v[0], delta[1]+v[1], delta[2]+v[2], delta[3]+v[3]);
        t4[1] = make_float4(delta[4]+v[4], delta[5]+v[5], delta[6]+v[6], delta[7]+v[7]);

        parity ^= 1;
        cur = nxt;   // register move; dead after the last row
    }
}

// Fallback for shapes where T != BLOCK*CHUNK: one thread per row, sequential.
__global__ void gae_naive_kernel(
    const float* __restrict__ rewards,
    const float* __restrict__ values,
    const float* __restrict__ next_value,
    const int*   __restrict__ done,
    float* __restrict__ adv_out,
    float* __restrict__ ret_out,
    int B, int T)
{
    int row = blockIdx.x * blockDim.x + threadIdx.x;
    if (row >= B) return;
    long base = (long)row * T;
    float g = 0.0f;
    for (int t = T - 1; t >= 0; --t) {
        int dcol = (t + 1 < T) ? (t + 1) : (T - 1);
        float nnt = 1.0f - (float)done[base + dcol];
        float nv  = (t + 1 < T) ? values[base + t + 1] : next_value[row];
        float dl  = rewards[base + t] + GAMMA * nv * nnt - values[base + t];
        g = dl + (GAMMA * LAM) * nnt * g;
        adv_out[base + t] = g;
        ret_out[base + t] = g + values[base + t];
    }
}

extern "C" void kernel_launch(void* const* d_in, const int* in_sizes, int n_in,
                              void* d_out, int out_size, void* d_ws, size_t ws_size,
                              hipStream_t stream) {
    const float* rewards    = (const float*)d_in[0];
    const float* values     = (const float*)d_in[1];
    const float* next_value = (const float*)d_in[2];
    const int*   done       = (const int*)d_in[3];

    const int B = in_sizes[2];               // next_value is [B]
    const int T = in_sizes[0] / B;           // rewards is [B, T]

    float* adv = (float*)d_out;
    float* ret = adv + (long)B * T;

    if (T == BLOCK * CHUNK) {
        const int grid = (B < GRID_TARGET) ? B : GRID_TARGET;
        gae_scan_kernel<<<grid, BLOCK, 0, stream>>>(
            rewards, values, next_value, done, adv, ret, B, T);
    } else {
        gae_naive_kernel<<<(B + 255) / 256, 256, 0, stream>>>(
            rewards, values, next_value, done, adv, ret, B, T);
    }
}

// Round 3
// 146.950 us; speedup vs baseline: 1.0382x; 1.0250x over previous
//
#include <hip/hip_runtime.h>

#define GAMMA 0.99f
#define LAM   0.95f

constexpr int BLOCK  = 512;          // 8 waves
constexpr int CHUNK  = 4;            // timesteps per thread; requires T == BLOCK*CHUNK
constexpr int NWAVES = BLOCK / 64;
constexpr int GRID_TARGET = 1024;    // 4 blocks/CU on 256 CUs -> 32 waves/CU resident

// Per-row register state (double-buffered across the row loop).
// All main loads are ONE lane-contiguous float4/int4 per array:
// thread tid covers [tid*4, tid*4+4) -> a wave's load = 1024B contiguous.
struct RowRegs {
    float4 ra, va;
    int4   da;
    float  bv;    // values[col0+CHUNK]            (lane 63 only)
    int    bd;    // done[min(col0+CHUNK, T-1)]    (lane 63 only)
    float  vboot; // next_value[row]               (tid == BLOCK-1 only)
};

__device__ __forceinline__ void load_row(
    const float* __restrict__ rewards, const float* __restrict__ values,
    const float* __restrict__ next_value, const int* __restrict__ done,
    int row, int T, int col0, int lane, int tid, RowRegs& R)
{
    const long rowbase = (long)row * T;
    R.ra = *reinterpret_cast<const float4*>(rewards + rowbase + col0);
    R.va = *reinterpret_cast<const float4*>(values  + rowbase + col0);
    R.da = *reinterpret_cast<const int4*>(done      + rowbase + col0);
    if (lane == 63) {
        const int bcol = (col0 + CHUNK < T) ? (col0 + CHUNK) : (T - 1);
        R.bv = values[rowbase + bcol];
        R.bd = done[rowbase + bcol];
    }
    if (tid == BLOCK - 1) R.vboot = next_value[row];
}

// One block per row-group (persistent over rows {bid + k*grid}). Backward
// linear recurrence g[t] = delta[t] + c[t]*g[t+1] via affine composition:
// per-thread 4-deep compose, 64-lane wave suffix-scan, 8-wave LDS combine.
__global__ __launch_bounds__(BLOCK, 8) void gae_scan_kernel(
    const float* __restrict__ rewards,
    const float* __restrict__ values,
    const float* __restrict__ next_value,
    const int*   __restrict__ done,
    float* __restrict__ adv_out,
    float* __restrict__ ret_out,
    int B, int T)
{
    const int tid  = threadIdx.x;
    const int lane = tid & 63;
    const int wave = tid >> 6;
    const int col0 = tid * CHUNK;

    __shared__ float lds_a[2][NWAVES];
    __shared__ float lds_m[2][NWAVES];

    RowRegs cur, nxt;
    load_row(rewards, values, next_value, done, blockIdx.x, T, col0, lane, tid, cur);

    int parity = 0;
    for (int row = blockIdx.x; row < B; row += gridDim.x) {
        // ---- prefetch next row while we compute this one ----
        const int nrow = row + gridDim.x;
        if (nrow < B)
            load_row(rewards, values, next_value, done, nrow, T, col0, lane, tid, nxt);

        const long rowbase = (long)row * T;

        // ---- unpack current row ----
        float v[CHUNK], r[CHUNK];
        v[0]=cur.va.x; v[1]=cur.va.y; v[2]=cur.va.z; v[3]=cur.va.w;
        r[0]=cur.ra.x; r[1]=cur.ra.y; r[2]=cur.ra.z; r[3]=cur.ra.w;

        // neighbor thread's first elements via intra-wave shuffle
        const float v_nb = __shfl_down(cur.va.x, 1);
        const int   d_nb = __shfl_down(cur.da.x, 1);
        float vnext  = (lane == 63) ? cur.bv : v_nb;          // values[col0+CHUNK]
        float dnextf = (float)((lane == 63) ? cur.bd : d_nb); // done[col0+CHUNK]
        if (tid == BLOCK - 1) vnext = cur.vboot;              // bootstrap at t=T-1

        // done[tcol+1] per owned tcol (in-register shift of the int4)
        float dn[CHUNK];
        dn[0]=(float)cur.da.y; dn[1]=(float)cur.da.z; dn[2]=(float)cur.da.w; dn[3]=dnextf;
        float nv[CHUNK];
        nv[0]=v[1]; nv[1]=v[2]; nv[2]=v[3]; nv[3]=vnext;

        // ---- delta[t] and c[t] ----
        float delta[CHUNK], c[CHUNK];
#pragma unroll
        for (int j = 0; j < CHUNK; ++j) {
            const float nnt = 1.0f - dn[j];
            delta[j] = r[j] + GAMMA * nv[j] * nnt - v[j];
            c[j]     = (GAMMA * LAM) * nnt;
        }

        // ---- per-thread affine composition over the chunk (backward) ----
        float a = 0.0f, m = 1.0f;
#pragma unroll
        for (int j = CHUNK - 1; j >= 0; --j) {
            a = delta[j] + c[j] * a;
            m = c[j] * m;
        }

        // ---- wave-level inclusive SUFFIX scan of affine fns ----
        float sa = a, sm = m;
#pragma unroll
        for (int d = 1; d < 64; d <<= 1) {
            float oa = __shfl_down(sa, d);
            float om = __shfl_down(sm, d);
            if (lane + d < 64) { sa = sa + sm * oa; sm = sm * om; }
        }
        float ea = __shfl_down(sa, 1);   // exclusive-within-wave
        float em = __shfl_down(sm, 1);
        if (lane == 63) { ea = 0.0f; em = 1.0f; }

        // ---- cross-wave composition via parity-buffered LDS ----
        if (lane == 0) { lds_a[parity][wave] = sa; lds_m[parity][wave] = sm; }
        __syncthreads();
        float g = 0.0f;
        for (int j = NWAVES - 1; j > wave; --j)
            g = lds_a[parity][j] + lds_m[parity][j] * g;
        float gin = ea + em * g;         // gae entering this thread's chunk

        // ---- replay: exact sequential recurrence over the chunk ----
#pragma unroll
        for (int j = CHUNK - 1; j >= 0; --j) {
            gin = delta[j] + c[j] * gin;
            delta[j] = gin;              // delta[] now holds advantages
        }

        // ---- lane-contiguous vectorized stores ----
        float4* a4 = reinterpret_cast<float4*>(adv_out + rowbase + col0);
        float4* t4 = reinterpret_cast<float4*>(ret_out + rowbase + col0);
        *a4 = make_float4(delta[0], delta[1], delta[2], delta[3]);
        *t4 = make_float4(delta[0]+v[0], delta[1]+v[1], delta[2]+v[2], delta[3]+v[3]);

        parity ^= 1;
        cur = nxt;   // register move; dead after the last row
    }
}

// Fallback for shapes where T != BLOCK*CHUNK: one thread per row, sequential.
__global__ void gae_naive_kernel(
    const float* __restrict__ rewards,
    const float* __restrict__ values,
    const float* __restrict__ next_value,
    const int*   __restrict__ done,
    float* __restrict__ adv_out,
    float* __restrict__ ret_out,
    int B, int T)
{
    int row = blockIdx.x * blockDim.x + threadIdx.x;
    if (row >= B) return;
    long base = (long)row * T;
    float g = 0.0f;
    for (int t = T - 1; t >= 0; --t) {
        int dcol = (t + 1 < T) ? (t + 1) : (T - 1);
        float nnt = 1.0f - (float)done[base + dcol];
        float nv  = (t + 1 < T) ? values[base + t + 1] : next_value[row];
        float dl  = rewards[base + t] + GAMMA * nv * nnt - values[base + t];
        g = dl + (GAMMA * LAM) * nnt * g;
        adv_out[base + t] = g;
        ret_out[base + t] = g + values[base + t];
    }
}

extern "C" void kernel_launch(void* const* d_in, const int* in_sizes, int n_in,
                              void* d_out, int out_size, void* d_ws, size_t ws_size,
                              hipStream_t stream) {
    const float* rewards    = (const float*)d_in[0];
    const float* values     = (const float*)d_in[1];
    const float* next_value = (const float*)d_in[2];
    const int*   done       = (const int*)d_in[3];

    const int B = in_sizes[2];               // next_value is [B]
    const int T = in_sizes[0] / B;           // rewards is [B, T]

    float* adv = (float*)d_out;
    float* ret = adv + (long)B * T;

    if (T == BLOCK * CHUNK) {
        const int grid = (B < GRID_TARGET) ? B : GRID_TARGET;
        gae_scan_kernel<<<grid, BLOCK, 0, stream>>>(
            rewards, values, next_value, done, adv, ret, B, T);
    } else {
        gae_naive_kernel<<<(B + 255) / 256, 256, 0, stream>>>(
            rewards, values, next_value, done, adv, ret, B, T);
    }
}